// Round 9
// baseline (24.845 us; speedup 1.0000x reference)
//
#include <hip/hip_runtime.h>

// Attentionlayer: B=4, T=12, N=1024, F_IN=64, F_OUT=64.
//
// Identity (verified R0-R8, absmax 1.6e-2 vs threshold 1.5e-1):
//   sum(softmax(att, axis=3), axis=3) == 1 for every (b,t,n) row, so
//   res = leaky_relu(h * 1) = leaky_relu(x @ W).
//
// R9: single-tile blocks ran device-wide phase-lockstep (load|compute|store
// serialize: ~2+2.6+2 us). Pipeline across 3 tiles per block: prefetch
// tile t+1 global->regs under compute(t); store(t) issues under the next
// tile's compute. 256 blocks x 512 thr, 2-buf swizzled x tile + single
// swizzled ot tile (syncthreads drains lgkmcnt -> read-then-rewrite safe),
// 48 KB LDS. Plain x loads (x/out are L3-resident across graph replays;
// NT loads would bypass), NT stores only. Everything else R5-proven:
// lane=row, wave=8-col slice, scalar-pipe W, XOR-swizzled tiles.

typedef float f32x4 __attribute__((ext_vector_type(4)));

constexpr int K     = 64;             // F_IN
constexpr int C     = 64;             // F_OUT
constexpr int ROWS  = 4 * 12 * 1024;  // 49152
constexpr int TR    = 64;             // rows per tile
constexpr int NC    = 8;              // cols per wave (8 waves cover 64)
constexpr int BT    = 512;            // block threads
constexpr int NTILE = 3;              // tiles per block
constexpr int GRID  = ROWS / (TR * NTILE);  // 256 blocks = 1/CU

__global__ __launch_bounds__(BT) void gat_fused_kernel(
    const float* __restrict__ x, const float* __restrict__ W,
    float* __restrict__ out) {
  __shared__ f32x4 xt[2][TR * 16];   // double-buffered swizzled x tile
  __shared__ f32x4 ot[TR * 16];      // swizzled out-transpose tile

  const int t    = threadIdx.x;
  const int lane = t & 63;           // row within tile
  const int wid  = t >> 6;           // wave id 0..7 -> 8-col slice
  const int c0   = __builtin_amdgcn_readfirstlane(wid * NC);

  const size_t base = (size_t)blockIdx.x * (TR * NTILE) * K;
  const f32x4* src  = reinterpret_cast<const f32x4*>(x + base);
  f32x4*       gdst = reinterpret_cast<f32x4*>(out + base);

  // ---- prologue: stage tile 0 (1024 f32x4 = 512 thr x 2) ----
  {
    f32x4 v0 = src[t], v1 = src[t + BT];
    int r0 = t >> 4,        cc0 = t & 15;
    int r1 = (t + BT) >> 4, cc1 = (t + BT) & 15;
    xt[0][r0 * 16 + (cc0 ^ (r0 & 15))] = v0;
    xt[0][r1 * 16 + (cc1 ^ (r1 & 15))] = v1;
  }
  __syncthreads();

#pragma unroll
  for (int tt = 0; tt < NTILE; ++tt) {
    const int buf = tt & 1;

    // issue next tile's global loads early; latency hides under compute
    f32x4 p0, p1;
    if (tt + 1 < NTILE) {
      p0 = src[(tt + 1) * 1024 + t];
      p1 = src[(tt + 1) * 1024 + t + BT];
    }

    // ---- compute: h[row][c0+j] = sum_k x[row][k] * W[k][c0+j] ----
    float acc[NC];
#pragma unroll
    for (int j = 0; j < NC; ++j) acc[j] = 0.f;
#pragma unroll
    for (int kq = 0; kq < 16; ++kq) {
      f32x4 xv = xt[buf][lane * 16 + (kq ^ (lane & 15))];  // own row, <=2-way
      const float* wr = W + (kq * 4) * C + c0;  // wave-uniform -> s_load
#pragma unroll
      for (int q = 0; q < 4; ++q) {
        const float* wk = wr + q * C;
        float xq = xv[q];
#pragma unroll
        for (int j = 0; j < NC; ++j)
          acc[j] = fmaf(xq, wk[j], acc[j]);    // v_fmac, SGPR W operand
      }
    }

    // ---- leaky_relu + swizzled transpose write ----
#pragma unroll
    for (int q = 0; q < NC / 4; ++q) {
      float a0 = acc[4 * q + 0], a1 = acc[4 * q + 1];
      float a2 = acc[4 * q + 2], a3 = acc[4 * q + 3];
      f32x4 v;
      v[0] = a0 > 0.f ? a0 : 0.01f * a0;
      v[1] = a1 > 0.f ? a1 : 0.01f * a1;
      v[2] = a2 > 0.f ? a2 : 0.01f * a2;
      v[3] = a3 > 0.f ? a3 : 0.01f * a3;
      int cq = (c0 >> 2) + q;
      ot[lane * 16 + (cq ^ (lane & 15))] = v;
    }
    __syncthreads();  // ot visible; xt[buf] fully consumed

    // ---- store tile tt (fire-and-forget) ----
    {
      int r0 = t >> 4,        cc0 = t & 15;
      int r1 = (t + BT) >> 4, cc1 = (t + BT) & 15;
      __builtin_nontemporal_store(ot[r0 * 16 + (cc0 ^ (r0 & 15))],
                                  gdst + tt * 1024 + t);
      __builtin_nontemporal_store(ot[r1 * 16 + (cc1 ^ (r1 & 15))],
                                  gdst + tt * 1024 + t + BT);
    }

    // ---- stage prefetched tile into the other buffer ----
    if (tt + 1 < NTILE) {
      int r0 = t >> 4,        cc0 = t & 15;
      int r1 = (t + BT) >> 4, cc1 = (t + BT) & 15;
      xt[buf ^ 1][r0 * 16 + (cc0 ^ (r0 & 15))] = p0;
      xt[buf ^ 1][r1 * 16 + (cc1 ^ (r1 & 15))] = p1;
    }
    __syncthreads();  // next xt buffer ready; ot reads drained
  }
}

extern "C" void kernel_launch(void* const* d_in, const int* in_sizes, int n_in,
                              void* d_out, int out_size, void* d_ws, size_t ws_size,
                              hipStream_t stream) {
  // setup_inputs order: x, adj, W, a. Only x and W matter (see identity).
  const float* x = (const float*)d_in[0];
  const float* W = (const float*)d_in[2];
  float* out     = (float*)d_out;

  dim3 grid(GRID);   // 256 blocks, 3 tiles each
  dim3 block(BT);
  gat_fused_kernel<<<grid, block, 0, stream>>>(x, W, out);
}

// Round 10
// 13.783 us; speedup vs baseline: 1.8026x; 1.8026x over previous
//
#include <hip/hip_runtime.h>

// Attentionlayer: B=4, T=12, N=1024, F_IN=64, F_OUT=64.
//
// Identity (verified R0-R9, absmax 1.6e-2 vs threshold 1.5e-1):
//   sum(softmax(att, axis=3), axis=3) == 1 for every (b,t,n) row, so
//   res = leaky_relu(h * 1) = leaky_relu(x @ W).
//
// R10 = R5 (best, 12.84us: 768 single-tile blocks x 512 thr, 24 waves/CU,
// lane=row, wave=8-col slice, scalar-pipe W, XOR-swizzled x tile, LDS
// out-transpose) + R8's swizzled ot tile (8-way -> <=2-way bank) but with
// ZERO nontemporal hints: NT loads bypass the L3 that keeps x resident
// across graph replays (R9 FETCH 7.3MB < 12.5MB proves L3 serves reads).
// R9 lesson: multi-tile blocks collapse occupancy (768 tiles / 256 CUs ->
// single-tile x 768 blocks is the only full-TLP config); cross-block
// wave overlap IS the pipeline.

typedef float f32x4 __attribute__((ext_vector_type(4)));

constexpr int K    = 64;             // F_IN
constexpr int C    = 64;             // F_OUT
constexpr int ROWS = 4 * 12 * 1024;  // 49152
constexpr int TR   = 64;             // rows per block
constexpr int NC   = 8;              // cols per wave (8 waves cover 64)
constexpr int BT   = 512;            // block threads

__global__ __launch_bounds__(BT) void gat_fused_kernel(
    const float* __restrict__ x, const float* __restrict__ W,
    float* __restrict__ out) {
  __shared__ f32x4 xt[TR * 16];      // swizzled x tile, 16 KB
  __shared__ f32x4 ot[TR * 16];      // swizzled out tile, 16 KB

  const int t    = threadIdx.x;
  const int lane = t & 63;  // row within tile
  const int wid  = t >> 6;  // wave id 0..7 -> 8-col slice
  const int c0   = __builtin_amdgcn_readfirstlane(wid * NC);
  const int row0 = (int)blockIdx.x * TR;

  // ---- Stage x tile (64x64 f32), XOR-swizzled; 512 thr x 2 f32x4 ----
  {
    const f32x4* src = reinterpret_cast<const f32x4*>(x + (size_t)row0 * K);
#pragma unroll
    for (int i = 0; i < 2; ++i) {
      int f = t + i * BT;            // 0..1023
      f32x4 v = src[f];              // coalesced 16B/lane, L3-friendly
      int r = f >> 4, cch = f & 15;
      xt[r * 16 + (cch ^ (r & 15))] = v;
    }
  }
  __syncthreads();

  // ---- Compute: h[row][c0+j] = sum_k x[row][k] * W[k][c0+j] ----
  float acc[NC];
#pragma unroll
  for (int j = 0; j < NC; ++j) acc[j] = 0.f;

#pragma unroll
  for (int kq = 0; kq < 16; ++kq) {
    f32x4 xv = xt[lane * 16 + (kq ^ (lane & 15))];  // own row, <=2-way
    const float* wr = W + (kq * 4) * C + c0;        // wave-uniform -> s_load
#pragma unroll
    for (int q = 0; q < 4; ++q) {
      const float* wk = wr + q * C;
      float xq = xv[q];
#pragma unroll
      for (int j = 0; j < NC; ++j)
        acc[j] = fmaf(xq, wk[j], acc[j]);  // v_fmac, SGPR W operand
    }
  }

  // ---- leaky_relu + swizzled transpose write (<=2-way banks) ----
#pragma unroll
  for (int q = 0; q < NC / 4; ++q) {
    float a0 = acc[4 * q + 0], a1 = acc[4 * q + 1];
    float a2 = acc[4 * q + 2], a3 = acc[4 * q + 3];
    f32x4 v;
    v[0] = a0 > 0.f ? a0 : 0.01f * a0;
    v[1] = a1 > 0.f ? a1 : 0.01f * a1;
    v[2] = a2 > 0.f ? a2 : 0.01f * a2;
    v[3] = a3 > 0.f ? a3 : 0.01f * a3;
    int cq = (c0 >> 2) + q;
    ot[lane * 16 + (cq ^ (lane & 15))] = v;
  }
  __syncthreads();

  // ---- Coalesced f32x4 stores of the transposed tile ----
  f32x4* gdst = reinterpret_cast<f32x4*>(out + (size_t)row0 * C);
#pragma unroll
  for (int i = 0; i < 2; ++i) {
    int f = t + i * BT;
    int r = f >> 4, cch = f & 15;
    gdst[f] = ot[r * 16 + (cch ^ (r & 15))];
  }
}

extern "C" void kernel_launch(void* const* d_in, const int* in_sizes, int n_in,
                              void* d_out, int out_size, void* d_ws, size_t ws_size,
                              hipStream_t stream) {
  // setup_inputs order: x, adj, W, a. Only x and W matter (see identity).
  const float* x = (const float*)d_in[0];
  const float* W = (const float*)d_in[2];
  float* out     = (float*)d_out;

  dim3 grid(ROWS / TR);  // 768 blocks, 3-4 resident/CU
  dim3 block(BT);
  gat_fused_kernel<<<grid, block, 0, stream>>>(x, W, out);
}

// Round 11
// 12.821 us; speedup vs baseline: 1.9378x; 1.0750x over previous
//
#include <hip/hip_runtime.h>

// Attentionlayer: B=4, T=12, N=1024, F_IN=64, F_OUT=64.
//
// Identity (verified R0-R10, absmax 1.6e-2 vs threshold 1.5e-1):
//   sum(softmax(att, axis=3), axis=3) == 1 for every (b,t,n) row, so
//   res = leaky_relu(h * 1) = leaky_relu(x @ W).
//
// R11 = byte-exact restore of R5, the best-measured variant (12.84 us).
// Full {ot-layout x NT} matrix measured: R5 stride-68/no-NT = 12.84;
// R8 swizzled/NT = 13.16; R10 swizzled/no-NT = 13.78. The ds_write_b128
// wave64 transpose write has a floor of 8 bank-accesses/bank regardless
// of layout (64 lanes x 4 banks / 32 banks), so the ot swizzle fixed a
// non-problem and its extra XOR addressing was pure cost.
// Structural attacks all regressed: async global_load_lds (R2: wc spill,
// +93MB scratch), in-block 3-tile pipeline (R9: 1 block/CU, occupancy
// collapse), NT hints (R8: bypass L3 that serves x across graph replays).
// Wins were: lane=row mapping with scalar-pipe W (R4, DS-issue 8x down)
// and 8-wave blocks + barrier trim (R5).

constexpr int K    = 64;             // F_IN
constexpr int C    = 64;             // F_OUT
constexpr int ROWS = 4 * 12 * 1024;  // 49152
constexpr int TR   = 64;             // rows per block
constexpr int NC   = 8;              // cols per wave (8 waves cover 64)
constexpr int BT   = 512;            // block threads

__global__ __launch_bounds__(BT) void gat_fused_kernel(
    const float* __restrict__ x, const float* __restrict__ W,
    float* __restrict__ out) {
  __shared__ float4 xt[TR * 16];     // swizzled x tile, 16 KB
  __shared__ float  ot[TR * 68];     // out transpose tile (+4 pad), 17 KB

  const int t    = threadIdx.x;
  const int lane = t & 63;  // row within tile
  const int wid  = t >> 6;  // wave id 0..7 -> 8-col slice
  const int c0   = __builtin_amdgcn_readfirstlane(wid * NC);
  const int row0 = (int)blockIdx.x * TR;

  // ---- Stage x tile (64x64 f32), XOR-swizzled; 512 thr x 2 float4 ----
  {
    const float4* src = reinterpret_cast<const float4*>(x + (size_t)row0 * K);
#pragma unroll
    for (int i = 0; i < 2; ++i) {
      int f = t + i * BT;            // 0..1023
      float4 v = src[f];             // coalesced 16B/lane
      int r = f >> 4, cch = f & 15;
      xt[r * 16 + (cch ^ (r & 15))] = v;
    }
  }
  __syncthreads();

  // ---- Compute: h[row][c0+j] = sum_k x[row][k] * W[k][c0+j] ----
  float acc[NC];
#pragma unroll
  for (int j = 0; j < NC; ++j) acc[j] = 0.f;

#pragma unroll
  for (int kq = 0; kq < 16; ++kq) {
    float4 xv = xt[lane * 16 + (kq ^ (lane & 15))];  // own row, 2-way max
    const float* wr = W + (kq * 4) * C + c0;         // wave-uniform -> s_load
#pragma unroll
    for (int q = 0; q < 4; ++q) {
      const float* wk = wr + q * C;
      float xq = (q == 0) ? xv.x : (q == 1) ? xv.y : (q == 2) ? xv.z : xv.w;
#pragma unroll
      for (int j = 0; j < NC; ++j)
        acc[j] = fmaf(xq, wk[j], acc[j]);  // v_fmac, SGPR W operand
    }
  }

  // ---- leaky_relu + transpose write (separate buffer: no barrier) ----
  float* orow = ot + lane * 68 + c0;
#pragma unroll
  for (int q = 0; q < NC / 4; ++q) {
    float a0 = acc[4 * q + 0], a1 = acc[4 * q + 1];
    float a2 = acc[4 * q + 2], a3 = acc[4 * q + 3];
    *reinterpret_cast<float4*>(orow + 4 * q) =
        make_float4(a0 > 0.f ? a0 : 0.01f * a0, a1 > 0.f ? a1 : 0.01f * a1,
                    a2 > 0.f ? a2 : 0.01f * a2, a3 > 0.f ? a3 : 0.01f * a3);
  }
  __syncthreads();

  // ---- Coalesced float4 stores of the transposed tile ----
  float4* gdst = reinterpret_cast<float4*>(out + (size_t)row0 * C);
#pragma unroll
  for (int i = 0; i < 2; ++i) {
    int f = t + i * BT;
    int r = f >> 4, cch = f & 15;
    gdst[f] = *reinterpret_cast<const float4*>(ot + r * 68 + cch * 4);
  }
}

extern "C" void kernel_launch(void* const* d_in, const int* in_sizes, int n_in,
                              void* d_out, int out_size, void* d_ws, size_t ws_size,
                              hipStream_t stream) {
  // setup_inputs order: x, adj, W, a. Only x and W matter (see identity).
  const float* x = (const float*)d_in[0];
  const float* W = (const float*)d_in[2];
  float* out     = (float*)d_out;

  dim3 grid(ROWS / TR);  // 768 blocks, 3 blocks/CU
  dim3 block(BT);
  gat_fused_kernel<<<grid, block, 0, stream>>>(x, W, out);
}